// Round 12
// baseline (211.545 us; speedup 1.0000x reference)
//
#include <hip/hip_runtime.h>
#include <hip/hip_fp16.h>
#include <cstdint>
#include <cstddef>

#define NNODES 10000
#define DIM 256
#define MNB 32
#define NT 79                // ceil(10000/128)
#define NTRI (NT*(NT+1)/2)   // 3160 upper-triangle tiles

typedef __attribute__((ext_vector_type(8))) _Float16 f16x8;
typedef __attribute__((ext_vector_type(4))) float f32x4;

__device__ inline unsigned short f16_rne(float f) {
    return __half_as_ushort(__float2half(f));
}
__device__ inline float f16_to_f32(unsigned short h) {
    return __half2float(__ushort_as_half(h));
}

// ---------------------------------------------------------------------------
// Kernel A (preprocessing, fused 1-D grid):
//   blocks [0,1250)      : split agg -> aggh/aggl
//   blocks [1250,2500)   : split node -> nodeh (hi only)
//   blocks [2500,2756)   : W [512,256] -> WT hi/lo [256,512]
// ---------------------------------------------------------------------------
__global__ __launch_bounds__(256) void pre_kernel(
    const float* __restrict__ agg, const float* __restrict__ node,
    const float* __restrict__ W,
    unsigned short* __restrict__ aggh, unsigned short* __restrict__ aggl,
    unsigned short* __restrict__ nodeh,
    unsigned short* __restrict__ wth, unsigned short* __restrict__ wtl)
{
    const int bx = blockIdx.x;
    const int t = threadIdx.x;
    const int count8 = NNODES * DIM / 8;   // 320000

    if (bx < 2500) {
        const int which = bx >= 1250;
        const int i = (which ? bx - 1250 : bx) * 256 + t;
        if (i >= count8) return;
        const float* in = which ? node : agg;
        float4 a = ((const float4*)in)[i * 2];
        float4 b = ((const float4*)in)[i * 2 + 1];
        float f[8] = {a.x, a.y, a.z, a.w, b.x, b.y, b.z, b.w};
        unsigned int hp[4], lp[4];
        #pragma unroll
        for (int j = 0; j < 4; ++j) {
            unsigned short h0 = f16_rne(f[2 * j]);
            unsigned short h1 = f16_rne(f[2 * j + 1]);
            hp[j] = (unsigned int)h0 | ((unsigned int)h1 << 16);
            if (!which) {
                unsigned short l0 = f16_rne(f[2 * j]     - f16_to_f32(h0));
                unsigned short l1 = f16_rne(f[2 * j + 1] - f16_to_f32(h1));
                lp[j] = (unsigned int)l0 | ((unsigned int)l1 << 16);
            }
        }
        if (which) {
            ((uint4*)nodeh)[i] = make_uint4(hp[0], hp[1], hp[2], hp[3]);
        } else {
            ((uint4*)aggh)[i] = make_uint4(hp[0], hp[1], hp[2], hp[3]);
            ((uint4*)aggl)[i] = make_uint4(lp[0], lp[1], lp[2], lp[3]);
        }
    } else {
        const int r = bx - 2500;           // 0..255
        #pragma unroll
        for (int h = 0; h < 2; ++h) {
            const int k = h * 256 + t;
            float v = W[(size_t)k * DIM + r];
            unsigned short hh = f16_rne(v);
            unsigned short ll = f16_rne(v - f16_to_f32(hh));
            wth[(size_t)r * 512 + k] = hh;
            wtl[(size_t)r * 512 + k] = ll;
        }
    }
}

// ---------------------------------------------------------------------------
// Kernel 1: attention context, fp16 gather path (R11-validated).
// ---------------------------------------------------------------------------
__global__ __launch_bounds__(256) void attn_ctx_kernel(
    const unsigned short* __restrict__ aggh,
    const int* __restrict__ nb_id,
    unsigned short* __restrict__ ctxh)
{
    const int n = blockIdx.x;
    const int t = threadIdx.x;
    __shared__ uint2 s_nb[MNB][64];    // 16 KB: fp16 neighbor rows
    __shared__ float s_score[MNB];
    __shared__ int   s_idx[MNB];

    if (t < MNB) s_idx[t] = nb_id[n * MNB + t];
    __syncthreads();

    const int wave = t >> 6;
    const int lane = t & 63;

    const uint2 q = ((const uint2*)aggh)[(size_t)n * 64 + lane];
    float qf[4];
    qf[0] = f16_to_f32((unsigned short)(q.x & 0xffff));
    qf[1] = f16_to_f32((unsigned short)(q.x >> 16));
    qf[2] = f16_to_f32((unsigned short)(q.y & 0xffff));
    qf[3] = f16_to_f32((unsigned short)(q.y >> 16));

    #pragma unroll
    for (int mi = 0; mi < 8; ++mi) {
        const int m = wave * 8 + mi;
        const int idx = s_idx[m];
        uint2 v = make_uint2(0u, 0u);
        if (idx >= 0) v = ((const uint2*)aggh)[(size_t)idx * 64 + lane];
        s_nb[m][lane] = v;
        float p = qf[0] * f16_to_f32((unsigned short)(v.x & 0xffff))
                + qf[1] * f16_to_f32((unsigned short)(v.x >> 16))
                + qf[2] * f16_to_f32((unsigned short)(v.y & 0xffff))
                + qf[3] * f16_to_f32((unsigned short)(v.y >> 16));
        #pragma unroll
        for (int off = 32; off; off >>= 1) p += __shfl_down(p, off);
        if (lane == 0) s_score[m] = (idx >= 0) ? p * (1.f / 16.f) : -6.25e8f;
    }
    __syncthreads();

    float mx = -INFINITY;
    #pragma unroll
    for (int m = 0; m < MNB; ++m) mx = fmaxf(mx, s_score[m]);
    float wgt[MNB];
    float denom = 0.f;
    #pragma unroll
    for (int m = 0; m < MNB; ++m) { wgt[m] = __expf(s_score[m] - mx); denom += wgt[m]; }
    const float inv = 1.f / denom;

    const __half* nbf = (const __half*)s_nb;
    float c = 0.f;
    #pragma unroll
    for (int m = 0; m < MNB; ++m)
        c = fmaf(wgt[m] * inv, __half2float(nbf[m * DIM + t]), c);

    ctxh[(size_t)n * DIM + t] = f16_rne(c);
}

// ---------------------------------------------------------------------------
// LDS layout: AH, BH, BL staged arrays, 16 KB each = 48 KB.
// Epilogue reuses bytes 0..32767 as a 64x128 f32 half-tile.
// ---------------------------------------------------------------------------
#define LDS_AH 0
#define LDS_BH 16384
#define LDS_BL 32768

// ---------------------------------------------------------------------------
// Kernel 2: decode_attribute = sigmoid([node|ctx] @ W + b), fp16 2-pass MFMA.
// (R7-validated)
// ---------------------------------------------------------------------------
__global__ __launch_bounds__(256, 3) void attr_mfma_kernel(
    const unsigned short* __restrict__ nodeh,
    const unsigned short* __restrict__ ctxh,
    const unsigned short* __restrict__ wth,
    const unsigned short* __restrict__ wtl,
    const float* __restrict__ bias,
    float* __restrict__ out)
{
    const int bj = blockIdx.x;        // 0..1
    const int bi = blockIdx.y;        // 0..78

    __shared__ __align__(16) char lds[49152];

    const int t = threadIdx.x;
    const int l = t & 63;
    const int w = t >> 6;
    const int wm = w >> 1;
    const int wn = w & 1;

    const int srow = t >> 1;
    const int shalf = t & 1;
    const int rowA = min(bi * 128 + srow, NNODES - 1);
    const size_t offA = (size_t)rowA * DIM;
    const int rowB = bj * 128 + srow;
    const size_t offB = (size_t)rowB * 512;

    f32x4 acc[4][4] = {};

    for (int kb = 0; kb < 512; kb += 64) {
        const unsigned short* aH = (kb < 256) ? nodeh : ctxh;
        const int koff = kb & 255;
        __syncthreads();
        #pragma unroll
        for (int c = 0; c < 4; ++c) {
            const int k8 = shalf * 4 + c;
            const int chp = k8 ^ (srow & 7);
            uint4 vah = *(const uint4*)&aH[offA + koff + k8 * 8];
            uint4 vbh = *(const uint4*)&wth[offB + kb + k8 * 8];
            uint4 vbl = *(const uint4*)&wtl[offB + kb + k8 * 8];
            *(uint4*)&lds[LDS_AH + srow * 128 + chp * 16] = vah;
            *(uint4*)&lds[LDS_BH + srow * 128 + chp * 16] = vbh;
            *(uint4*)&lds[LDS_BL + srow * 128 + chp * 16] = vbl;
        }
        __syncthreads();

        #pragma unroll
        for (int s = 0; s < 2; ++s) {
            f16x8 ah[4], bh[4], bl[4];
            #pragma unroll
            for (int m = 0; m < 4; ++m) {
                const int ra = wm * 64 + m * 16 + (l & 15);
                const int ca = (s * 4 + (l >> 4)) ^ (ra & 7);
                ah[m] = *(const f16x8*)&lds[LDS_AH + ra * 128 + ca * 16];
                const int rb = wn * 64 + m * 16 + (l & 15);
                const int cb = (s * 4 + (l >> 4)) ^ (rb & 7);
                bh[m] = *(const f16x8*)&lds[LDS_BH + rb * 128 + cb * 16];
                bl[m] = *(const f16x8*)&lds[LDS_BL + rb * 128 + cb * 16];
            }
            #pragma unroll
            for (int m = 0; m < 4; ++m)
                #pragma unroll
                for (int n = 0; n < 4; ++n) {
                    acc[m][n] = __builtin_amdgcn_mfma_f32_16x16x32_f16(ah[m], bh[n], acc[m][n], 0, 0, 0);
                    acc[m][n] = __builtin_amdgcn_mfma_f32_16x16x32_f16(ah[m], bl[n], acc[m][n], 0, 0, 0);
                }
        }
    }

    float bias_v[4];
    #pragma unroll
    for (int n = 0; n < 4; ++n)
        bias_v[n] = bias[bj * 128 + wn * 64 + n * 16 + (l & 15)];
    #pragma unroll
    for (int m = 0; m < 4; ++m)
        #pragma unroll
        for (int n = 0; n < 4; ++n)
            #pragma unroll
            for (int j = 0; j < 4; ++j)
                acc[m][n][j] = 1.f / (1.f + __expf(-(acc[m][n][j] + bias_v[n])));

    float* sf = (float*)lds;
    #pragma unroll
    for (int half = 0; half < 2; ++half) {
        __syncthreads();
        if (wm == half) {
            #pragma unroll
            for (int m = 0; m < 4; ++m)
                #pragma unroll
                for (int n = 0; n < 4; ++n)
                    #pragma unroll
                    for (int j = 0; j < 4; ++j) {
                        const int r = m * 16 + (l >> 4) * 4 + j;   // 0..63
                        const int c = wn * 64 + n * 16 + (l & 15);
                        sf[r * 128 + c] = acc[m][n][j];
                    }
        }
        __syncthreads();
        const int c4 = t & 31;
        const int gc = bj * 128 + c4 * 4;
        #pragma unroll
        for (int it = 0; it < 8; ++it) {
            const int r = it * 8 + (t >> 5);
            const int gr = bi * 128 + half * 64 + r;
            if (gr < NNODES) {
                float4 v = *(float4*)&sf[r * 128 + c4 * 4];
                *(float4*)&out[(size_t)gr * DIM + gc] = v;
            }
        }
    }
}

// ---------------------------------------------------------------------------
// Kernel 3: decode_adj = sigmoid(agg @ agg^T), fp16 2-pass MFMA.
// R11 structure; epilogue stores are PLAIN (L2 write-back) instead of nt so
// barrier vmcnt drains complete at L2 (~200cy) not HBM (~900cy).
// ---------------------------------------------------------------------------
__global__ __launch_bounds__(256, 3) void adj_mfma_kernel(
    const unsigned short* __restrict__ aggh,
    const unsigned short* __restrict__ aggl,
    float* __restrict__ out)
{
    const int tid = blockIdx.x;
    int bi = (int)((2 * NT + 1 - sqrtf((float)((2 * NT + 1) * (2 * NT + 1)) - 8.0f * (float)tid)) * 0.5f);
    while (bi > 0 && bi * NT - bi * (bi - 1) / 2 > tid) --bi;
    while ((bi + 1) * NT - (bi + 1) * bi / 2 <= tid) ++bi;
    const int bj = bi + (tid - (bi * NT - bi * (bi - 1) / 2));

    __shared__ __align__(16) char lds[49152];

    const int t = threadIdx.x;
    const int l = t & 63;
    const int w = t >> 6;
    const int wm = w >> 1;
    const int wn = w & 1;

    const int srow = t >> 1;
    const int shalf = t & 1;
    const int rowA = min(bi * 128 + srow, NNODES - 1);
    const int rowB = min(bj * 128 + srow, NNODES - 1);
    const size_t offA = (size_t)rowA * DIM;
    const size_t offB = (size_t)rowB * DIM;

    f32x4 acc[4][4] = {};

    for (int kb = 0; kb < DIM; kb += 64) {
        __syncthreads();
        #pragma unroll
        for (int c = 0; c < 4; ++c) {
            const int k8 = shalf * 4 + c;
            const int chp = k8 ^ (srow & 7);
            uint4 vah = *(const uint4*)&aggh[offA + kb + k8 * 8];
            uint4 vbh = *(const uint4*)&aggh[offB + kb + k8 * 8];
            uint4 vbl = *(const uint4*)&aggl[offB + kb + k8 * 8];
            *(uint4*)&lds[LDS_AH + srow * 128 + chp * 16] = vah;
            *(uint4*)&lds[LDS_BH + srow * 128 + chp * 16] = vbh;
            *(uint4*)&lds[LDS_BL + srow * 128 + chp * 16] = vbl;
        }
        __syncthreads();

        #pragma unroll
        for (int s = 0; s < 2; ++s) {
            f16x8 ah[4], bh[4], bl[4];
            #pragma unroll
            for (int m = 0; m < 4; ++m) {
                const int ra = wm * 64 + m * 16 + (l & 15);
                const int ca = (s * 4 + (l >> 4)) ^ (ra & 7);
                ah[m] = *(const f16x8*)&lds[LDS_AH + ra * 128 + ca * 16];
                const int rb = wn * 64 + m * 16 + (l & 15);
                const int cb = (s * 4 + (l >> 4)) ^ (rb & 7);
                bh[m] = *(const f16x8*)&lds[LDS_BH + rb * 128 + cb * 16];
                bl[m] = *(const f16x8*)&lds[LDS_BL + rb * 128 + cb * 16];
            }
            #pragma unroll
            for (int m = 0; m < 4; ++m)
                #pragma unroll
                for (int n = 0; n < 4; ++n) {
                    acc[m][n] = __builtin_amdgcn_mfma_f32_16x16x32_f16(ah[m], bh[n], acc[m][n], 0, 0, 0);
                    acc[m][n] = __builtin_amdgcn_mfma_f32_16x16x32_f16(ah[m], bl[n], acc[m][n], 0, 0, 0);
                }
        }
    }

    #pragma unroll
    for (int m = 0; m < 4; ++m)
        #pragma unroll
        for (int n = 0; n < 4; ++n)
            #pragma unroll
            for (int j = 0; j < 4; ++j)
                acc[m][n][j] = 1.f / (1.f + __expf(-acc[m][n][j]));

    float* sf = (float*)lds;
    const size_t NN = NNODES;

    // ---- pass 1: normal orientation, two 64-row halves (plain stores)
    #pragma unroll
    for (int half = 0; half < 2; ++half) {
        __syncthreads();
        if (wm == half) {
            #pragma unroll
            for (int m = 0; m < 4; ++m)
                #pragma unroll
                for (int n = 0; n < 4; ++n)
                    #pragma unroll
                    for (int j = 0; j < 4; ++j) {
                        const int r = m * 16 + (l >> 4) * 4 + j;   // 0..63
                        const int c = wn * 64 + n * 16 + (l & 15);
                        sf[r * 128 + c] = acc[m][n][j];
                    }
        }
        __syncthreads();
        const int c4 = t & 31;
        const int gc = bj * 128 + c4 * 4;
        #pragma unroll
        for (int it = 0; it < 8; ++it) {
            const int r = it * 8 + (t >> 5);
            const int gr = bi * 128 + half * 64 + r;
            if (gr < NNODES && gc < NNODES) {
                f32x4 v = *(f32x4*)&sf[r * 128 + c4 * 4];
                *(f32x4*)&out[(size_t)gr * NN + gc] = v;
            }
        }
    }

    // ---- pass 2: transposed image for the mirror tile (skip on diagonal)
    if (bi != bj) {
        #pragma unroll
        for (int half = 0; half < 2; ++half) {
            __syncthreads();
            if (wn == half) {
                #pragma unroll
                for (int m = 0; m < 4; ++m)
                    #pragma unroll
                    for (int n = 0; n < 4; ++n)
                        #pragma unroll
                        for (int j = 0; j < 4; ++j) {
                            const int r = wm * 64 + m * 16 + (l >> 4) * 4 + j;
                            const int c = n * 16 + (l & 15);       // 0..63
                            sf[c * 128 + (((r >> 2) ^ (c & 7)) << 2) + (r & 3)] = acc[m][n][j];
                        }
            }
            __syncthreads();
            const int g = t & 31;
            const int gc2 = bi * 128 + g * 4;       // bi <= 77 -> in range
            #pragma unroll
            for (int it = 0; it < 8; ++it) {
                const int rt = it * 8 + (t >> 5);   // 0..63 within half
                const int gr2 = bj * 128 + half * 64 + rt;
                if (gr2 < NNODES) {
                    f32x4 v = *(f32x4*)&sf[rt * 128 + ((g ^ (rt & 7)) << 2)];
                    *(f32x4*)&out[(size_t)gr2 * NN + gc2] = v;
                }
            }
        }
    }
}

extern "C" void kernel_launch(void* const* d_in, const int* in_sizes, int n_in,
                              void* d_out, int out_size, void* d_ws, size_t ws_size,
                              hipStream_t stream) {
    const float* node = (const float*)d_in[0];
    const float* agg  = (const float*)d_in[1];
    const int*   nb   = (const int*)d_in[2];
    const float* W    = (const float*)d_in[3];
    const float* bias = (const float*)d_in[4];

    float* out_attr = (float*)d_out;
    float* out_adj  = (float*)d_out + (size_t)NNODES * DIM;

    char* ws = (char*)d_ws;
    unsigned short* aggh  = (unsigned short*)(ws);
    unsigned short* aggl  = (unsigned short*)(ws + 5120000);
    unsigned short* nodeh = (unsigned short*)(ws + 10240000);
    unsigned short* ctxh  = (unsigned short*)(ws + 15360000);
    unsigned short* wth   = (unsigned short*)(ws + 20480000);
    unsigned short* wtl   = (unsigned short*)(ws + 21004288);

    pre_kernel<<<2756, 256, 0, stream>>>(agg, node, W, aggh, aggl, nodeh, wth, wtl);

    adj_mfma_kernel<<<NTRI, 256, 0, stream>>>(aggh, aggl, out_adj);

    attn_ctx_kernel<<<NNODES, 256, 0, stream>>>(aggh, nb, ctxh);

    dim3 g2(2, NT);
    attr_mfma_kernel<<<g2, 256, 0, stream>>>(nodeh, ctxh, wth, wtl, bias, out_attr);
}

// Round 13
// 174.826 us; speedup vs baseline: 1.2100x; 1.2100x over previous
//
#include <hip/hip_runtime.h>
#include <hip/hip_fp16.h>
#include <cstdint>
#include <cstddef>

#define NNODES 10000
#define DIM 256
#define MNB 32
#define NT 79                // ceil(10000/128)
#define NTRI (NT*(NT+1)/2)   // 3160 upper-triangle tiles

typedef __attribute__((ext_vector_type(8))) _Float16 f16x8;
typedef __attribute__((ext_vector_type(4))) float f32x4;

__device__ inline unsigned short f16_rne(float f) {
    return __half_as_ushort(__float2half(f));
}
__device__ inline float f16_to_f32(unsigned short h) {
    return __half2float(__ushort_as_half(h));
}

// ---------------------------------------------------------------------------
// Kernel 0: split two f32 arrays into fp16 HI arrays (lo no longer needed).
// ---------------------------------------------------------------------------
__global__ __launch_bounds__(256) void split2_kernel(
    const float* __restrict__ in0, const float* __restrict__ in1,
    unsigned short* __restrict__ hi0, unsigned short* __restrict__ hi1,
    int count8)
{
    const int i = blockIdx.x * 256 + threadIdx.x;
    if (i >= count8) return;
    const float* in = blockIdx.y ? in1 : in0;
    unsigned short* hi = blockIdx.y ? hi1 : hi0;
    float4 a = ((const float4*)in)[i * 2];
    float4 b = ((const float4*)in)[i * 2 + 1];
    float f[8] = {a.x, a.y, a.z, a.w, b.x, b.y, b.z, b.w};
    unsigned int hp[4];
    #pragma unroll
    for (int j = 0; j < 4; ++j) {
        unsigned short h0 = f16_rne(f[2 * j]);
        unsigned short h1 = f16_rne(f[2 * j + 1]);
        hp[j] = (unsigned int)h0 | ((unsigned int)h1 << 16);
    }
    ((uint4*)hi)[i] = make_uint4(hp[0], hp[1], hp[2], hp[3]);
}

// ---------------------------------------------------------------------------
// Kernel 0b: W [512,256] -> WT hi/lo [256,512] (transpose + split).
// ---------------------------------------------------------------------------
__global__ __launch_bounds__(256) void wt_split_kernel(
    const float* __restrict__ W,
    unsigned short* __restrict__ wth,
    unsigned short* __restrict__ wtl)
{
    const int r = blockIdx.x;
    const int t = threadIdx.x;
    #pragma unroll
    for (int h = 0; h < 2; ++h) {
        const int k = h * 256 + t;
        float v = W[(size_t)k * DIM + r];
        unsigned short hh = f16_rne(v);
        unsigned short ll = f16_rne(v - f16_to_f32(hh));
        wth[(size_t)r * 512 + k] = hh;
        wtl[(size_t)r * 512 + k] = ll;
    }
}

// ---------------------------------------------------------------------------
// Kernel 1: attention context, fp16 gather path (R11-validated).
// ---------------------------------------------------------------------------
__global__ __launch_bounds__(256) void attn_ctx_kernel(
    const unsigned short* __restrict__ aggh,
    const int* __restrict__ nb_id,
    unsigned short* __restrict__ ctxh)
{
    const int n = blockIdx.x;
    const int t = threadIdx.x;
    __shared__ uint2 s_nb[MNB][64];    // 16 KB: fp16 neighbor rows
    __shared__ float s_score[MNB];
    __shared__ int   s_idx[MNB];

    if (t < MNB) s_idx[t] = nb_id[n * MNB + t];
    __syncthreads();

    const int wave = t >> 6;
    const int lane = t & 63;

    const uint2 q = ((const uint2*)aggh)[(size_t)n * 64 + lane];
    float qf[4];
    qf[0] = f16_to_f32((unsigned short)(q.x & 0xffff));
    qf[1] = f16_to_f32((unsigned short)(q.x >> 16));
    qf[2] = f16_to_f32((unsigned short)(q.y & 0xffff));
    qf[3] = f16_to_f32((unsigned short)(q.y >> 16));

    #pragma unroll
    for (int mi = 0; mi < 8; ++mi) {
        const int m = wave * 8 + mi;
        const int idx = s_idx[m];
        uint2 v = make_uint2(0u, 0u);
        if (idx >= 0) v = ((const uint2*)aggh)[(size_t)idx * 64 + lane];
        s_nb[m][lane] = v;
        float p = qf[0] * f16_to_f32((unsigned short)(v.x & 0xffff))
                + qf[1] * f16_to_f32((unsigned short)(v.x >> 16))
                + qf[2] * f16_to_f32((unsigned short)(v.y & 0xffff))
                + qf[3] * f16_to_f32((unsigned short)(v.y >> 16));
        #pragma unroll
        for (int off = 32; off; off >>= 1) p += __shfl_down(p, off);
        if (lane == 0) s_score[m] = (idx >= 0) ? p * (1.f / 16.f) : -6.25e8f;
    }
    __syncthreads();

    float mx = -INFINITY;
    #pragma unroll
    for (int m = 0; m < MNB; ++m) mx = fmaxf(mx, s_score[m]);
    float wgt[MNB];
    float denom = 0.f;
    #pragma unroll
    for (int m = 0; m < MNB; ++m) { wgt[m] = __expf(s_score[m] - mx); denom += wgt[m]; }
    const float inv = 1.f / denom;

    const __half* nbf = (const __half*)s_nb;
    float c = 0.f;
    #pragma unroll
    for (int m = 0; m < MNB; ++m)
        c = fmaf(wgt[m] * inv, __half2float(nbf[m * DIM + t]), c);

    ctxh[(size_t)n * DIM + t] = f16_rne(c);
}

// ---------------------------------------------------------------------------
// Kernel 2: decode_attribute = sigmoid([node|ctx] @ W + b), fp16 2-pass MFMA.
// (R7-validated; unchanged)
// ---------------------------------------------------------------------------
#define ALDS_AH 0
#define ALDS_BH 16384
#define ALDS_BL 32768

__global__ __launch_bounds__(256, 3) void attr_mfma_kernel(
    const unsigned short* __restrict__ nodeh,
    const unsigned short* __restrict__ ctxh,
    const unsigned short* __restrict__ wth,
    const unsigned short* __restrict__ wtl,
    const float* __restrict__ bias,
    float* __restrict__ out)
{
    const int bj = blockIdx.x;        // 0..1
    const int bi = blockIdx.y;        // 0..78

    __shared__ __align__(16) char lds[49152];

    const int t = threadIdx.x;
    const int l = t & 63;
    const int w = t >> 6;
    const int wm = w >> 1;
    const int wn = w & 1;

    const int srow = t >> 1;
    const int shalf = t & 1;
    const int rowA = min(bi * 128 + srow, NNODES - 1);
    const size_t offA = (size_t)rowA * DIM;
    const int rowB = bj * 128 + srow;
    const size_t offB = (size_t)rowB * 512;

    f32x4 acc[4][4] = {};

    for (int kb = 0; kb < 512; kb += 64) {
        const unsigned short* aH = (kb < 256) ? nodeh : ctxh;
        const int koff = kb & 255;
        __syncthreads();
        #pragma unroll
        for (int c = 0; c < 4; ++c) {
            const int k8 = shalf * 4 + c;
            const int chp = k8 ^ (srow & 7);
            uint4 vah = *(const uint4*)&aH[offA + koff + k8 * 8];
            uint4 vbh = *(const uint4*)&wth[offB + kb + k8 * 8];
            uint4 vbl = *(const uint4*)&wtl[offB + kb + k8 * 8];
            *(uint4*)&lds[ALDS_AH + srow * 128 + chp * 16] = vah;
            *(uint4*)&lds[ALDS_BH + srow * 128 + chp * 16] = vbh;
            *(uint4*)&lds[ALDS_BL + srow * 128 + chp * 16] = vbl;
        }
        __syncthreads();

        #pragma unroll
        for (int s = 0; s < 2; ++s) {
            f16x8 ah[4], bh[4], bl[4];
            #pragma unroll
            for (int m = 0; m < 4; ++m) {
                const int ra = wm * 64 + m * 16 + (l & 15);
                const int ca = (s * 4 + (l >> 4)) ^ (ra & 7);
                ah[m] = *(const f16x8*)&lds[ALDS_AH + ra * 128 + ca * 16];
                const int rb = wn * 64 + m * 16 + (l & 15);
                const int cb = (s * 4 + (l >> 4)) ^ (rb & 7);
                bh[m] = *(const f16x8*)&lds[ALDS_BH + rb * 128 + cb * 16];
                bl[m] = *(const f16x8*)&lds[ALDS_BL + rb * 128 + cb * 16];
            }
            #pragma unroll
            for (int m = 0; m < 4; ++m)
                #pragma unroll
                for (int n = 0; n < 4; ++n) {
                    acc[m][n] = __builtin_amdgcn_mfma_f32_16x16x32_f16(ah[m], bh[n], acc[m][n], 0, 0, 0);
                    acc[m][n] = __builtin_amdgcn_mfma_f32_16x16x32_f16(ah[m], bl[n], acc[m][n], 0, 0, 0);
                }
        }
    }

    float bias_v[4];
    #pragma unroll
    for (int n = 0; n < 4; ++n)
        bias_v[n] = bias[bj * 128 + wn * 64 + n * 16 + (l & 15)];
    #pragma unroll
    for (int m = 0; m < 4; ++m)
        #pragma unroll
        for (int n = 0; n < 4; ++n)
            #pragma unroll
            for (int j = 0; j < 4; ++j)
                acc[m][n][j] = 1.f / (1.f + __expf(-(acc[m][n][j] + bias_v[n])));

    float* sf = (float*)lds;
    #pragma unroll
    for (int half = 0; half < 2; ++half) {
        __syncthreads();
        if (wm == half) {
            #pragma unroll
            for (int m = 0; m < 4; ++m)
                #pragma unroll
                for (int n = 0; n < 4; ++n)
                    #pragma unroll
                    for (int j = 0; j < 4; ++j) {
                        const int r = m * 16 + (l >> 4) * 4 + j;   // 0..63
                        const int c = wn * 64 + n * 16 + (l & 15);
                        sf[r * 128 + c] = acc[m][n][j];
                    }
        }
        __syncthreads();
        const int c4 = t & 31;
        const int gc = bj * 128 + c4 * 4;
        #pragma unroll
        for (int it = 0; it < 8; ++it) {
            const int r = it * 8 + (t >> 5);
            const int gr = bi * 128 + half * 64 + r;
            if (gr < NNODES) {
                float4 v = *(float4*)&sf[r * 128 + c4 * 4];
                *(float4*)&out[(size_t)gr * DIM + gc] = v;
            }
        }
    }
}

// ---------------------------------------------------------------------------
// Kernel 3: decode_adj = sigmoid(agg @ agg^T), fp16 1-PASS MFMA (Ah*Bh only;
// dropped Al*B + Ah*Bl terms -> predicted absmax ~0.009-0.012 vs 0.02).
// LDS: AH+BH = 32 KB -> 4-5 blocks/CU. Epilogue: R11-validated dual-pass
// half-tile repack with nontemporal full-line stores.
// ---------------------------------------------------------------------------
#define LDS_AH 0
#define LDS_BH 16384

__global__ __launch_bounds__(256, 4) void adj_mfma_kernel(
    const unsigned short* __restrict__ aggh,
    float* __restrict__ out)
{
    const int tid = blockIdx.x;
    int bi = (int)((2 * NT + 1 - sqrtf((float)((2 * NT + 1) * (2 * NT + 1)) - 8.0f * (float)tid)) * 0.5f);
    while (bi > 0 && bi * NT - bi * (bi - 1) / 2 > tid) --bi;
    while ((bi + 1) * NT - (bi + 1) * bi / 2 <= tid) ++bi;
    const int bj = bi + (tid - (bi * NT - bi * (bi - 1) / 2));

    __shared__ __align__(16) char lds[32768];

    const int t = threadIdx.x;
    const int l = t & 63;
    const int w = t >> 6;
    const int wm = w >> 1;
    const int wn = w & 1;

    const int srow = t >> 1;
    const int shalf = t & 1;
    const int rowA = min(bi * 128 + srow, NNODES - 1);
    const int rowB = min(bj * 128 + srow, NNODES - 1);
    const size_t offA = (size_t)rowA * DIM;
    const size_t offB = (size_t)rowB * DIM;

    f32x4 acc[4][4] = {};

    for (int kb = 0; kb < DIM; kb += 64) {
        __syncthreads();
        #pragma unroll
        for (int c = 0; c < 4; ++c) {
            const int k8 = shalf * 4 + c;
            const int chp = k8 ^ (srow & 7);
            uint4 vah = *(const uint4*)&aggh[offA + kb + k8 * 8];
            uint4 vbh = *(const uint4*)&aggh[offB + kb + k8 * 8];
            *(uint4*)&lds[LDS_AH + srow * 128 + chp * 16] = vah;
            *(uint4*)&lds[LDS_BH + srow * 128 + chp * 16] = vbh;
        }
        __syncthreads();

        #pragma unroll
        for (int s = 0; s < 2; ++s) {
            f16x8 ah[4], bh[4];
            #pragma unroll
            for (int m = 0; m < 4; ++m) {
                const int ra = wm * 64 + m * 16 + (l & 15);
                const int ca = (s * 4 + (l >> 4)) ^ (ra & 7);
                ah[m] = *(const f16x8*)&lds[LDS_AH + ra * 128 + ca * 16];
                const int rb = wn * 64 + m * 16 + (l & 15);
                const int cb = (s * 4 + (l >> 4)) ^ (rb & 7);
                bh[m] = *(const f16x8*)&lds[LDS_BH + rb * 128 + cb * 16];
            }
            #pragma unroll
            for (int m = 0; m < 4; ++m)
                #pragma unroll
                for (int n = 0; n < 4; ++n)
                    acc[m][n] = __builtin_amdgcn_mfma_f32_16x16x32_f16(ah[m], bh[n], acc[m][n], 0, 0, 0);
        }
    }

    #pragma unroll
    for (int m = 0; m < 4; ++m)
        #pragma unroll
        for (int n = 0; n < 4; ++n)
            #pragma unroll
            for (int j = 0; j < 4; ++j)
                acc[m][n][j] = 1.f / (1.f + __expf(-acc[m][n][j]));

    float* sf = (float*)lds;
    const size_t NN = NNODES;

    // ---- pass 1: normal orientation, two 64-row halves (nt stores)
    #pragma unroll
    for (int half = 0; half < 2; ++half) {
        __syncthreads();
        if (wm == half) {
            #pragma unroll
            for (int m = 0; m < 4; ++m)
                #pragma unroll
                for (int n = 0; n < 4; ++n)
                    #pragma unroll
                    for (int j = 0; j < 4; ++j) {
                        const int r = m * 16 + (l >> 4) * 4 + j;   // 0..63
                        const int c = wn * 64 + n * 16 + (l & 15);
                        sf[r * 128 + c] = acc[m][n][j];
                    }
        }
        __syncthreads();
        const int c4 = t & 31;
        const int gc = bj * 128 + c4 * 4;
        #pragma unroll
        for (int it = 0; it < 8; ++it) {
            const int r = it * 8 + (t >> 5);
            const int gr = bi * 128 + half * 64 + r;
            if (gr < NNODES && gc < NNODES) {
                f32x4 v = *(f32x4*)&sf[r * 128 + c4 * 4];
                __builtin_nontemporal_store(v, (f32x4*)&out[(size_t)gr * NN + gc]);
            }
        }
    }

    // ---- pass 2: transposed image for the mirror tile (skip on diagonal)
    if (bi != bj) {
        #pragma unroll
        for (int half = 0; half < 2; ++half) {
            __syncthreads();
            if (wn == half) {
                #pragma unroll
                for (int m = 0; m < 4; ++m)
                    #pragma unroll
                    for (int n = 0; n < 4; ++n)
                        #pragma unroll
                        for (int j = 0; j < 4; ++j) {
                            const int r = wm * 64 + m * 16 + (l >> 4) * 4 + j;
                            const int c = n * 16 + (l & 15);       // 0..63
                            sf[c * 128 + (((r >> 2) ^ (c & 7)) << 2) + (r & 3)] = acc[m][n][j];
                        }
            }
            __syncthreads();
            const int g = t & 31;
            const int gc2 = bi * 128 + g * 4;       // bi <= 77 -> in range
            #pragma unroll
            for (int it = 0; it < 8; ++it) {
                const int rt = it * 8 + (t >> 5);   // 0..63 within half
                const int gr2 = bj * 128 + half * 64 + rt;
                if (gr2 < NNODES) {
                    f32x4 v = *(f32x4*)&sf[rt * 128 + ((g ^ (rt & 7)) << 2)];
                    __builtin_nontemporal_store(v, (f32x4*)&out[(size_t)gr2 * NN + gc2]);
                }
            }
        }
    }
}

extern "C" void kernel_launch(void* const* d_in, const int* in_sizes, int n_in,
                              void* d_out, int out_size, void* d_ws, size_t ws_size,
                              hipStream_t stream) {
    const float* node = (const float*)d_in[0];
    const float* agg  = (const float*)d_in[1];
    const int*   nb   = (const int*)d_in[2];
    const float* W    = (const float*)d_in[3];
    const float* bias = (const float*)d_in[4];

    float* out_attr = (float*)d_out;
    float* out_adj  = (float*)d_out + (size_t)NNODES * DIM;

    char* ws = (char*)d_ws;
    unsigned short* aggh  = (unsigned short*)(ws);
    unsigned short* nodeh = (unsigned short*)(ws + 5120000);
    unsigned short* ctxh  = (unsigned short*)(ws + 10240000);
    unsigned short* wth   = (unsigned short*)(ws + 15360000);
    unsigned short* wtl   = (unsigned short*)(ws + 15884288);

    const int count8 = NNODES * DIM / 8;
    dim3 gs((count8 + 255) / 256, 2);
    split2_kernel<<<gs, 256, 0, stream>>>(agg, node, aggh, nodeh, count8);

    adj_mfma_kernel<<<NTRI, 256, 0, stream>>>(aggh, out_adj);

    wt_split_kernel<<<256, 256, 0, stream>>>(W, wth, wtl);
    attn_ctx_kernel<<<NNODES, 256, 0, stream>>>(aggh, nb, ctxh);

    dim3 g2(2, NT);
    attr_mfma_kernel<<<g2, 256, 0, stream>>>(nodeh, ctxh, wth, wtl, bias, out_attr);
}

// Round 14
// 171.248 us; speedup vs baseline: 1.2353x; 1.0209x over previous
//
#include <hip/hip_runtime.h>
#include <hip/hip_fp16.h>
#include <cstdint>
#include <cstddef>

#define NNODES 10000
#define DIM 256
#define MNB 32
#define NT 79                // ceil(10000/128)
#define NTRI (NT*(NT+1)/2)   // 3160 upper-triangle tiles

typedef __attribute__((ext_vector_type(8))) _Float16 f16x8;
typedef __attribute__((ext_vector_type(4))) float f32x4;

__device__ inline unsigned short f16_rne(float f) {
    return __half_as_ushort(__float2half(f));
}
__device__ inline float f16_to_f32(unsigned short h) {
    return __half2float(__ushort_as_half(h));
}

// ---------------------------------------------------------------------------
// Kernel A (preprocessing, fused 1-D grid):
//   blocks [0,1250)    : agg  -> aggh  (fp16 hi)
//   blocks [1250,2500) : node -> nodeh (fp16 hi)
//   blocks [2500,2756) : W [512,256] -> WT hi [256,512] (transpose)
// ---------------------------------------------------------------------------
__global__ __launch_bounds__(256) void pre_kernel(
    const float* __restrict__ agg, const float* __restrict__ node,
    const float* __restrict__ W,
    unsigned short* __restrict__ aggh,
    unsigned short* __restrict__ nodeh,
    unsigned short* __restrict__ wth)
{
    const int bx = blockIdx.x;
    const int t = threadIdx.x;
    const int count8 = NNODES * DIM / 8;   // 320000

    if (bx < 2500) {
        const int which = bx >= 1250;
        const int i = (which ? bx - 1250 : bx) * 256 + t;
        if (i >= count8) return;
        const float* in = which ? node : agg;
        unsigned short* hi = which ? nodeh : aggh;
        float4 a = ((const float4*)in)[i * 2];
        float4 b = ((const float4*)in)[i * 2 + 1];
        float f[8] = {a.x, a.y, a.z, a.w, b.x, b.y, b.z, b.w};
        unsigned int hp[4];
        #pragma unroll
        for (int j = 0; j < 4; ++j) {
            unsigned short h0 = f16_rne(f[2 * j]);
            unsigned short h1 = f16_rne(f[2 * j + 1]);
            hp[j] = (unsigned int)h0 | ((unsigned int)h1 << 16);
        }
        ((uint4*)hi)[i] = make_uint4(hp[0], hp[1], hp[2], hp[3]);
    } else {
        const int r = bx - 2500;           // 0..255
        #pragma unroll
        for (int h = 0; h < 2; ++h) {
            const int k = h * 256 + t;
            wth[(size_t)r * 512 + k] = f16_rne(W[(size_t)k * DIM + r]);
        }
    }
}

// ---------------------------------------------------------------------------
// Kernel 1: attention context, fp16 gather path (R11-validated).
// ---------------------------------------------------------------------------
__global__ __launch_bounds__(256) void attn_ctx_kernel(
    const unsigned short* __restrict__ aggh,
    const int* __restrict__ nb_id,
    unsigned short* __restrict__ ctxh)
{
    const int n = blockIdx.x;
    const int t = threadIdx.x;
    __shared__ uint2 s_nb[MNB][64];    // 16 KB: fp16 neighbor rows
    __shared__ float s_score[MNB];
    __shared__ int   s_idx[MNB];

    if (t < MNB) s_idx[t] = nb_id[n * MNB + t];
    __syncthreads();

    const int wave = t >> 6;
    const int lane = t & 63;

    const uint2 q = ((const uint2*)aggh)[(size_t)n * 64 + lane];
    float qf[4];
    qf[0] = f16_to_f32((unsigned short)(q.x & 0xffff));
    qf[1] = f16_to_f32((unsigned short)(q.x >> 16));
    qf[2] = f16_to_f32((unsigned short)(q.y & 0xffff));
    qf[3] = f16_to_f32((unsigned short)(q.y >> 16));

    #pragma unroll
    for (int mi = 0; mi < 8; ++mi) {
        const int m = wave * 8 + mi;
        const int idx = s_idx[m];
        uint2 v = make_uint2(0u, 0u);
        if (idx >= 0) v = ((const uint2*)aggh)[(size_t)idx * 64 + lane];
        s_nb[m][lane] = v;
        float p = qf[0] * f16_to_f32((unsigned short)(v.x & 0xffff))
                + qf[1] * f16_to_f32((unsigned short)(v.x >> 16))
                + qf[2] * f16_to_f32((unsigned short)(v.y & 0xffff))
                + qf[3] * f16_to_f32((unsigned short)(v.y >> 16));
        #pragma unroll
        for (int off = 32; off; off >>= 1) p += __shfl_down(p, off);
        if (lane == 0) s_score[m] = (idx >= 0) ? p * (1.f / 16.f) : -6.25e8f;
    }
    __syncthreads();

    float mx = -INFINITY;
    #pragma unroll
    for (int m = 0; m < MNB; ++m) mx = fmaxf(mx, s_score[m]);
    float wgt[MNB];
    float denom = 0.f;
    #pragma unroll
    for (int m = 0; m < MNB; ++m) { wgt[m] = __expf(s_score[m] - mx); denom += wgt[m]; }
    const float inv = 1.f / denom;

    const __half* nbf = (const __half*)s_nb;
    float c = 0.f;
    #pragma unroll
    for (int m = 0; m < MNB; ++m)
        c = fmaf(wgt[m] * inv, __half2float(nbf[m * DIM + t]), c);

    ctxh[(size_t)n * DIM + t] = f16_rne(c);
}

// ---------------------------------------------------------------------------
// Kernel 2: decode_attribute = sigmoid([node|ctx] @ W + b), fp16 1-PASS MFMA
// (Ah*Wh only; dropped terms ~1.4e-4 logit sigma). LDS 32 KB -> 4 blocks/CU.
// ---------------------------------------------------------------------------
#define ALDS_AH 0
#define ALDS_BH 16384

__global__ __launch_bounds__(256, 4) void attr_mfma_kernel(
    const unsigned short* __restrict__ nodeh,
    const unsigned short* __restrict__ ctxh,
    const unsigned short* __restrict__ wth,
    const float* __restrict__ bias,
    float* __restrict__ out)
{
    const int bj = blockIdx.x;        // 0..1
    const int bi = blockIdx.y;        // 0..78

    __shared__ __align__(16) char lds[32768];

    const int t = threadIdx.x;
    const int l = t & 63;
    const int w = t >> 6;
    const int wm = w >> 1;
    const int wn = w & 1;

    const int srow = t >> 1;
    const int shalf = t & 1;
    const int rowA = min(bi * 128 + srow, NNODES - 1);
    const size_t offA = (size_t)rowA * DIM;
    const int rowB = bj * 128 + srow;
    const size_t offB = (size_t)rowB * 512;

    f32x4 acc[4][4] = {};

    for (int kb = 0; kb < 512; kb += 64) {
        const unsigned short* aH = (kb < 256) ? nodeh : ctxh;
        const int koff = kb & 255;
        __syncthreads();
        #pragma unroll
        for (int c = 0; c < 4; ++c) {
            const int k8 = shalf * 4 + c;
            const int chp = k8 ^ (srow & 7);
            uint4 vah = *(const uint4*)&aH[offA + koff + k8 * 8];
            uint4 vbh = *(const uint4*)&wth[offB + kb + k8 * 8];
            *(uint4*)&lds[ALDS_AH + srow * 128 + chp * 16] = vah;
            *(uint4*)&lds[ALDS_BH + srow * 128 + chp * 16] = vbh;
        }
        __syncthreads();

        #pragma unroll
        for (int s = 0; s < 2; ++s) {
            f16x8 ah[4], bh[4];
            #pragma unroll
            for (int m = 0; m < 4; ++m) {
                const int ra = wm * 64 + m * 16 + (l & 15);
                const int ca = (s * 4 + (l >> 4)) ^ (ra & 7);
                ah[m] = *(const f16x8*)&lds[ALDS_AH + ra * 128 + ca * 16];
                const int rb = wn * 64 + m * 16 + (l & 15);
                const int cb = (s * 4 + (l >> 4)) ^ (rb & 7);
                bh[m] = *(const f16x8*)&lds[ALDS_BH + rb * 128 + cb * 16];
            }
            #pragma unroll
            for (int m = 0; m < 4; ++m)
                #pragma unroll
                for (int n = 0; n < 4; ++n)
                    acc[m][n] = __builtin_amdgcn_mfma_f32_16x16x32_f16(ah[m], bh[n], acc[m][n], 0, 0, 0);
        }
    }

    float bias_v[4];
    #pragma unroll
    for (int n = 0; n < 4; ++n)
        bias_v[n] = bias[bj * 128 + wn * 64 + n * 16 + (l & 15)];
    #pragma unroll
    for (int m = 0; m < 4; ++m)
        #pragma unroll
        for (int n = 0; n < 4; ++n)
            #pragma unroll
            for (int j = 0; j < 4; ++j)
                acc[m][n][j] = 1.f / (1.f + __expf(-(acc[m][n][j] + bias_v[n])));

    float* sf = (float*)lds;
    #pragma unroll
    for (int half = 0; half < 2; ++half) {
        __syncthreads();
        if (wm == half) {
            #pragma unroll
            for (int m = 0; m < 4; ++m)
                #pragma unroll
                for (int n = 0; n < 4; ++n)
                    #pragma unroll
                    for (int j = 0; j < 4; ++j) {
                        const int r = m * 16 + (l >> 4) * 4 + j;   // 0..63
                        const int c = wn * 64 + n * 16 + (l & 15);
                        sf[r * 128 + c] = acc[m][n][j];
                    }
        }
        __syncthreads();
        const int c4 = t & 31;
        const int gc = bj * 128 + c4 * 4;
        #pragma unroll
        for (int it = 0; it < 8; ++it) {
            const int r = it * 8 + (t >> 5);
            const int gr = bi * 128 + half * 64 + r;
            if (gr < NNODES) {
                float4 v = *(float4*)&sf[r * 128 + c4 * 4];
                *(float4*)&out[(size_t)gr * DIM + gc] = v;
            }
        }
    }
}

// ---------------------------------------------------------------------------
// Kernel 3: decode_adj = sigmoid(agg @ agg^T), fp16 1-pass MFMA
// (R13-validated, unchanged).
// ---------------------------------------------------------------------------
#define LDS_AH 0
#define LDS_BH 16384

__global__ __launch_bounds__(256, 4) void adj_mfma_kernel(
    const unsigned short* __restrict__ aggh,
    float* __restrict__ out)
{
    const int tid = blockIdx.x;
    int bi = (int)((2 * NT + 1 - sqrtf((float)((2 * NT + 1) * (2 * NT + 1)) - 8.0f * (float)tid)) * 0.5f);
    while (bi > 0 && bi * NT - bi * (bi - 1) / 2 > tid) --bi;
    while ((bi + 1) * NT - (bi + 1) * bi / 2 <= tid) ++bi;
    const int bj = bi + (tid - (bi * NT - bi * (bi - 1) / 2));

    __shared__ __align__(16) char lds[32768];

    const int t = threadIdx.x;
    const int l = t & 63;
    const int w = t >> 6;
    const int wm = w >> 1;
    const int wn = w & 1;

    const int srow = t >> 1;
    const int shalf = t & 1;
    const int rowA = min(bi * 128 + srow, NNODES - 1);
    const int rowB = min(bj * 128 + srow, NNODES - 1);
    const size_t offA = (size_t)rowA * DIM;
    const size_t offB = (size_t)rowB * DIM;

    f32x4 acc[4][4] = {};

    for (int kb = 0; kb < DIM; kb += 64) {
        __syncthreads();
        #pragma unroll
        for (int c = 0; c < 4; ++c) {
            const int k8 = shalf * 4 + c;
            const int chp = k8 ^ (srow & 7);
            uint4 vah = *(const uint4*)&aggh[offA + kb + k8 * 8];
            uint4 vbh = *(const uint4*)&aggh[offB + kb + k8 * 8];
            *(uint4*)&lds[LDS_AH + srow * 128 + chp * 16] = vah;
            *(uint4*)&lds[LDS_BH + srow * 128 + chp * 16] = vbh;
        }
        __syncthreads();

        #pragma unroll
        for (int s = 0; s < 2; ++s) {
            f16x8 ah[4], bh[4];
            #pragma unroll
            for (int m = 0; m < 4; ++m) {
                const int ra = wm * 64 + m * 16 + (l & 15);
                const int ca = (s * 4 + (l >> 4)) ^ (ra & 7);
                ah[m] = *(const f16x8*)&lds[LDS_AH + ra * 128 + ca * 16];
                const int rb = wn * 64 + m * 16 + (l & 15);
                const int cb = (s * 4 + (l >> 4)) ^ (rb & 7);
                bh[m] = *(const f16x8*)&lds[LDS_BH + rb * 128 + cb * 16];
            }
            #pragma unroll
            for (int m = 0; m < 4; ++m)
                #pragma unroll
                for (int n = 0; n < 4; ++n)
                    acc[m][n] = __builtin_amdgcn_mfma_f32_16x16x32_f16(ah[m], bh[n], acc[m][n], 0, 0, 0);
        }
    }

    #pragma unroll
    for (int m = 0; m < 4; ++m)
        #pragma unroll
        for (int n = 0; n < 4; ++n)
            #pragma unroll
            for (int j = 0; j < 4; ++j)
                acc[m][n][j] = 1.f / (1.f + __expf(-acc[m][n][j]));

    float* sf = (float*)lds;
    const size_t NN = NNODES;

    // ---- pass 1: normal orientation, two 64-row halves (nt stores)
    #pragma unroll
    for (int half = 0; half < 2; ++half) {
        __syncthreads();
        if (wm == half) {
            #pragma unroll
            for (int m = 0; m < 4; ++m)
                #pragma unroll
                for (int n = 0; n < 4; ++n)
                    #pragma unroll
                    for (int j = 0; j < 4; ++j) {
                        const int r = m * 16 + (l >> 4) * 4 + j;   // 0..63
                        const int c = wn * 64 + n * 16 + (l & 15);
                        sf[r * 128 + c] = acc[m][n][j];
                    }
        }
        __syncthreads();
        const int c4 = t & 31;
        const int gc = bj * 128 + c4 * 4;
        #pragma unroll
        for (int it = 0; it < 8; ++it) {
            const int r = it * 8 + (t >> 5);
            const int gr = bi * 128 + half * 64 + r;
            if (gr < NNODES && gc < NNODES) {
                f32x4 v = *(f32x4*)&sf[r * 128 + c4 * 4];
                __builtin_nontemporal_store(v, (f32x4*)&out[(size_t)gr * NN + gc]);
            }
        }
    }

    // ---- pass 2: transposed image for the mirror tile (skip on diagonal)
    if (bi != bj) {
        #pragma unroll
        for (int half = 0; half < 2; ++half) {
            __syncthreads();
            if (wn == half) {
                #pragma unroll
                for (int m = 0; m < 4; ++m)
                    #pragma unroll
                    for (int n = 0; n < 4; ++n)
                        #pragma unroll
                        for (int j = 0; j < 4; ++j) {
                            const int r = wm * 64 + m * 16 + (l >> 4) * 4 + j;
                            const int c = n * 16 + (l & 15);       // 0..63
                            sf[c * 128 + (((r >> 2) ^ (c & 7)) << 2) + (r & 3)] = acc[m][n][j];
                        }
            }
            __syncthreads();
            const int g = t & 31;
            const int gc2 = bi * 128 + g * 4;       // bi <= 77 -> in range
            #pragma unroll
            for (int it = 0; it < 8; ++it) {
                const int rt = it * 8 + (t >> 5);   // 0..63 within half
                const int gr2 = bj * 128 + half * 64 + rt;
                if (gr2 < NNODES) {
                    f32x4 v = *(f32x4*)&sf[rt * 128 + ((g ^ (rt & 7)) << 2)];
                    __builtin_nontemporal_store(v, (f32x4*)&out[(size_t)gr2 * NN + gc2]);
                }
            }
        }
    }
}

extern "C" void kernel_launch(void* const* d_in, const int* in_sizes, int n_in,
                              void* d_out, int out_size, void* d_ws, size_t ws_size,
                              hipStream_t stream) {
    const float* node = (const float*)d_in[0];
    const float* agg  = (const float*)d_in[1];
    const int*   nb   = (const int*)d_in[2];
    const float* W    = (const float*)d_in[3];
    const float* bias = (const float*)d_in[4];

    float* out_attr = (float*)d_out;
    float* out_adj  = (float*)d_out + (size_t)NNODES * DIM;

    char* ws = (char*)d_ws;
    unsigned short* aggh  = (unsigned short*)(ws);
    unsigned short* nodeh = (unsigned short*)(ws + 5120000);
    unsigned short* ctxh  = (unsigned short*)(ws + 10240000);
    unsigned short* wth   = (unsigned short*)(ws + 15360000);

    pre_kernel<<<2756, 256, 0, stream>>>(agg, node, W, aggh, nodeh, wth);

    adj_mfma_kernel<<<NTRI, 256, 0, stream>>>(aggh, out_adj);

    attn_ctx_kernel<<<NNODES, 256, 0, stream>>>(aggh, nb, ctxh);

    dim3 g2(2, NT);
    attr_mfma_kernel<<<g2, 256, 0, stream>>>(nodeh, ctxh, wth, bias, out_attr);
}

// Round 15
// 167.017 us; speedup vs baseline: 1.2666x; 1.0253x over previous
//
#include <hip/hip_runtime.h>
#include <hip/hip_fp16.h>
#include <cstdint>
#include <cstddef>

#define NNODES 10000
#define DIM 256
#define MNB 32
#define NT 79                // ceil(10000/128)
#define NTRI (NT*(NT+1)/2)   // 3160 upper-triangle tiles

typedef __attribute__((ext_vector_type(8))) _Float16 f16x8;
typedef __attribute__((ext_vector_type(4))) float f32x4;

__device__ inline unsigned short f16_rne(float f) {
    return __half_as_ushort(__float2half(f));
}
__device__ inline float f16_to_f32(unsigned short h) {
    return __half2float(__ushort_as_half(h));
}

// Barrier that waits only on LDS ops (lgkmcnt), NOT on outstanding global
// stores (vmcnt) — __syncthreads would drain nt stores to HBM (~1000cy).
// Safe here: all cross-wave hazards in adj are LDS-only; global loads are
// ordered before their dependent ds_writes by compiler-inserted vmcnt waits,
// and stores capture VGPR data at issue. sched_barrier fences per rule #18.
__device__ inline void lds_barrier() {
    __builtin_amdgcn_sched_barrier(0);
    asm volatile("s_waitcnt lgkmcnt(0)" ::: "memory");
    __builtin_amdgcn_sched_barrier(0);
    __builtin_amdgcn_s_barrier();
    __builtin_amdgcn_sched_barrier(0);
}

// ---------------------------------------------------------------------------
// Kernel A (preprocessing, fused 1-D grid):
//   blocks [0,1250)    : agg  -> aggh  (fp16 hi)
//   blocks [1250,2500) : node -> nodeh (fp16 hi)
//   blocks [2500,2756) : W [512,256] -> WT hi [256,512] (transpose)
// ---------------------------------------------------------------------------
__global__ __launch_bounds__(256) void pre_kernel(
    const float* __restrict__ agg, const float* __restrict__ node,
    const float* __restrict__ W,
    unsigned short* __restrict__ aggh,
    unsigned short* __restrict__ nodeh,
    unsigned short* __restrict__ wth)
{
    const int bx = blockIdx.x;
    const int t = threadIdx.x;
    const int count8 = NNODES * DIM / 8;   // 320000

    if (bx < 2500) {
        const int which = bx >= 1250;
        const int i = (which ? bx - 1250 : bx) * 256 + t;
        if (i >= count8) return;
        const float* in = which ? node : agg;
        unsigned short* hi = which ? nodeh : aggh;
        float4 a = ((const float4*)in)[i * 2];
        float4 b = ((const float4*)in)[i * 2 + 1];
        float f[8] = {a.x, a.y, a.z, a.w, b.x, b.y, b.z, b.w};
        unsigned int hp[4];
        #pragma unroll
        for (int j = 0; j < 4; ++j) {
            unsigned short h0 = f16_rne(f[2 * j]);
            unsigned short h1 = f16_rne(f[2 * j + 1]);
            hp[j] = (unsigned int)h0 | ((unsigned int)h1 << 16);
        }
        ((uint4*)hi)[i] = make_uint4(hp[0], hp[1], hp[2], hp[3]);
    } else {
        const int r = bx - 2500;           // 0..255
        #pragma unroll
        for (int h = 0; h < 2; ++h) {
            const int k = h * 256 + t;
            wth[(size_t)r * 512 + k] = f16_rne(W[(size_t)k * DIM + r]);
        }
    }
}

// ---------------------------------------------------------------------------
// Kernel 1: attention context, fp16 gather path (R11-validated).
// ---------------------------------------------------------------------------
__global__ __launch_bounds__(256) void attn_ctx_kernel(
    const unsigned short* __restrict__ aggh,
    const int* __restrict__ nb_id,
    unsigned short* __restrict__ ctxh)
{
    const int n = blockIdx.x;
    const int t = threadIdx.x;
    __shared__ uint2 s_nb[MNB][64];    // 16 KB: fp16 neighbor rows
    __shared__ float s_score[MNB];
    __shared__ int   s_idx[MNB];

    if (t < MNB) s_idx[t] = nb_id[n * MNB + t];
    __syncthreads();

    const int wave = t >> 6;
    const int lane = t & 63;

    const uint2 q = ((const uint2*)aggh)[(size_t)n * 64 + lane];
    float qf[4];
    qf[0] = f16_to_f32((unsigned short)(q.x & 0xffff));
    qf[1] = f16_to_f32((unsigned short)(q.x >> 16));
    qf[2] = f16_to_f32((unsigned short)(q.y & 0xffff));
    qf[3] = f16_to_f32((unsigned short)(q.y >> 16));

    #pragma unroll
    for (int mi = 0; mi < 8; ++mi) {
        const int m = wave * 8 + mi;
        const int idx = s_idx[m];
        uint2 v = make_uint2(0u, 0u);
        if (idx >= 0) v = ((const uint2*)aggh)[(size_t)idx * 64 + lane];
        s_nb[m][lane] = v;
        float p = qf[0] * f16_to_f32((unsigned short)(v.x & 0xffff))
                + qf[1] * f16_to_f32((unsigned short)(v.x >> 16))
                + qf[2] * f16_to_f32((unsigned short)(v.y & 0xffff))
                + qf[3] * f16_to_f32((unsigned short)(v.y >> 16));
        #pragma unroll
        for (int off = 32; off; off >>= 1) p += __shfl_down(p, off);
        if (lane == 0) s_score[m] = (idx >= 0) ? p * (1.f / 16.f) : -6.25e8f;
    }
    __syncthreads();

    float mx = -INFINITY;
    #pragma unroll
    for (int m = 0; m < MNB; ++m) mx = fmaxf(mx, s_score[m]);
    float wgt[MNB];
    float denom = 0.f;
    #pragma unroll
    for (int m = 0; m < MNB; ++m) { wgt[m] = __expf(s_score[m] - mx); denom += wgt[m]; }
    const float inv = 1.f / denom;

    const __half* nbf = (const __half*)s_nb;
    float c = 0.f;
    #pragma unroll
    for (int m = 0; m < MNB; ++m)
        c = fmaf(wgt[m] * inv, __half2float(nbf[m * DIM + t]), c);

    ctxh[(size_t)n * DIM + t] = f16_rne(c);
}

// ---------------------------------------------------------------------------
// Kernel 2: decode_attribute = sigmoid([node|ctx] @ W + b), fp16 1-pass MFMA
// (R14-validated, unchanged).
// ---------------------------------------------------------------------------
#define ALDS_AH 0
#define ALDS_BH 16384

__global__ __launch_bounds__(256, 4) void attr_mfma_kernel(
    const unsigned short* __restrict__ nodeh,
    const unsigned short* __restrict__ ctxh,
    const unsigned short* __restrict__ wth,
    const float* __restrict__ bias,
    float* __restrict__ out)
{
    const int bj = blockIdx.x;        // 0..1
    const int bi = blockIdx.y;        // 0..78

    __shared__ __align__(16) char lds[32768];

    const int t = threadIdx.x;
    const int l = t & 63;
    const int w = t >> 6;
    const int wm = w >> 1;
    const int wn = w & 1;

    const int srow = t >> 1;
    const int shalf = t & 1;
    const int rowA = min(bi * 128 + srow, NNODES - 1);
    const size_t offA = (size_t)rowA * DIM;
    const int rowB = bj * 128 + srow;
    const size_t offB = (size_t)rowB * 512;

    f32x4 acc[4][4] = {};

    for (int kb = 0; kb < 512; kb += 64) {
        const unsigned short* aH = (kb < 256) ? nodeh : ctxh;
        const int koff = kb & 255;
        __syncthreads();
        #pragma unroll
        for (int c = 0; c < 4; ++c) {
            const int k8 = shalf * 4 + c;
            const int chp = k8 ^ (srow & 7);
            uint4 vah = *(const uint4*)&aH[offA + koff + k8 * 8];
            uint4 vbh = *(const uint4*)&wth[offB + kb + k8 * 8];
            *(uint4*)&lds[ALDS_AH + srow * 128 + chp * 16] = vah;
            *(uint4*)&lds[ALDS_BH + srow * 128 + chp * 16] = vbh;
        }
        __syncthreads();

        #pragma unroll
        for (int s = 0; s < 2; ++s) {
            f16x8 ah[4], bh[4];
            #pragma unroll
            for (int m = 0; m < 4; ++m) {
                const int ra = wm * 64 + m * 16 + (l & 15);
                const int ca = (s * 4 + (l >> 4)) ^ (ra & 7);
                ah[m] = *(const f16x8*)&lds[ALDS_AH + ra * 128 + ca * 16];
                const int rb = wn * 64 + m * 16 + (l & 15);
                const int cb = (s * 4 + (l >> 4)) ^ (rb & 7);
                bh[m] = *(const f16x8*)&lds[ALDS_BH + rb * 128 + cb * 16];
            }
            #pragma unroll
            for (int m = 0; m < 4; ++m)
                #pragma unroll
                for (int n = 0; n < 4; ++n)
                    acc[m][n] = __builtin_amdgcn_mfma_f32_16x16x32_f16(ah[m], bh[n], acc[m][n], 0, 0, 0);
        }
    }

    float bias_v[4];
    #pragma unroll
    for (int n = 0; n < 4; ++n)
        bias_v[n] = bias[bj * 128 + wn * 64 + n * 16 + (l & 15)];
    #pragma unroll
    for (int m = 0; m < 4; ++m)
        #pragma unroll
        for (int n = 0; n < 4; ++n)
            #pragma unroll
            for (int j = 0; j < 4; ++j)
                acc[m][n][j] = 1.f / (1.f + __expf(-(acc[m][n][j] + bias_v[n])));

    float* sf = (float*)lds;
    #pragma unroll
    for (int half = 0; half < 2; ++half) {
        __syncthreads();
        if (wm == half) {
            #pragma unroll
            for (int m = 0; m < 4; ++m)
                #pragma unroll
                for (int n = 0; n < 4; ++n)
                    #pragma unroll
                    for (int j = 0; j < 4; ++j) {
                        const int r = m * 16 + (l >> 4) * 4 + j;   // 0..63
                        const int c = wn * 64 + n * 16 + (l & 15);
                        sf[r * 128 + c] = acc[m][n][j];
                    }
        }
        __syncthreads();
        const int c4 = t & 31;
        const int gc = bj * 128 + c4 * 4;
        #pragma unroll
        for (int it = 0; it < 8; ++it) {
            const int r = it * 8 + (t >> 5);
            const int gr = bi * 128 + half * 64 + r;
            if (gr < NNODES) {
                float4 v = *(float4*)&sf[r * 128 + c4 * 4];
                *(float4*)&out[(size_t)gr * DIM + gc] = v;
            }
        }
    }
}

// ---------------------------------------------------------------------------
// Kernel 3: decode_adj = sigmoid(agg @ agg^T), fp16 1-pass MFMA.
// R14 structure; ALL barriers are lgk-only (lds_barrier) so nt stores never
// drain at a barrier — the only vmcnt waits left are compiler-inserted
// data-dependent ones (staged load -> ds_write).
// ---------------------------------------------------------------------------
#define LDS_AH 0
#define LDS_BH 16384

__global__ __launch_bounds__(256, 4) void adj_mfma_kernel(
    const unsigned short* __restrict__ aggh,
    float* __restrict__ out)
{
    const int tid = blockIdx.x;
    int bi = (int)((2 * NT + 1 - sqrtf((float)((2 * NT + 1) * (2 * NT + 1)) - 8.0f * (float)tid)) * 0.5f);
    while (bi > 0 && bi * NT - bi * (bi - 1) / 2 > tid) --bi;
    while ((bi + 1) * NT - (bi + 1) * bi / 2 <= tid) ++bi;
    const int bj = bi + (tid - (bi * NT - bi * (bi - 1) / 2));

    __shared__ __align__(16) char lds[32768];

    const int t = threadIdx.x;
    const int l = t & 63;
    const int w = t >> 6;
    const int wm = w >> 1;
    const int wn = w & 1;

    const int srow = t >> 1;
    const int shalf = t & 1;
    const int rowA = min(bi * 128 + srow, NNODES - 1);
    const int rowB = min(bj * 128 + srow, NNODES - 1);
    const size_t offA = (size_t)rowA * DIM;
    const size_t offB = (size_t)rowB * DIM;

    f32x4 acc[4][4] = {};

    for (int kb = 0; kb < DIM; kb += 64) {
        lds_barrier();
        #pragma unroll
        for (int c = 0; c < 4; ++c) {
            const int k8 = shalf * 4 + c;
            const int chp = k8 ^ (srow & 7);
            uint4 vah = *(const uint4*)&aggh[offA + kb + k8 * 8];
            uint4 vbh = *(const uint4*)&aggh[offB + kb + k8 * 8];
            *(uint4*)&lds[LDS_AH + srow * 128 + chp * 16] = vah;
            *(uint4*)&lds[LDS_BH + srow * 128 + chp * 16] = vbh;
        }
        lds_barrier();

        #pragma unroll
        for (int s = 0; s < 2; ++s) {
            f16x8 ah[4], bh[4];
            #pragma unroll
            for (int m = 0; m < 4; ++m) {
                const int ra = wm * 64 + m * 16 + (l & 15);
                const int ca = (s * 4 + (l >> 4)) ^ (ra & 7);
                ah[m] = *(const f16x8*)&lds[LDS_AH + ra * 128 + ca * 16];
                const int rb = wn * 64 + m * 16 + (l & 15);
                const int cb = (s * 4 + (l >> 4)) ^ (rb & 7);
                bh[m] = *(const f16x8*)&lds[LDS_BH + rb * 128 + cb * 16];
            }
            #pragma unroll
            for (int m = 0; m < 4; ++m)
                #pragma unroll
                for (int n = 0; n < 4; ++n)
                    acc[m][n] = __builtin_amdgcn_mfma_f32_16x16x32_f16(ah[m], bh[n], acc[m][n], 0, 0, 0);
        }
    }

    #pragma unroll
    for (int m = 0; m < 4; ++m)
        #pragma unroll
        for (int n = 0; n < 4; ++n)
            #pragma unroll
            for (int j = 0; j < 4; ++j)
                acc[m][n][j] = 1.f / (1.f + __expf(-acc[m][n][j]));

    float* sf = (float*)lds;
    const size_t NN = NNODES;

    // ---- pass 1: normal orientation, two 64-row halves (nt stores)
    #pragma unroll
    for (int half = 0; half < 2; ++half) {
        lds_barrier();
        if (wm == half) {
            #pragma unroll
            for (int m = 0; m < 4; ++m)
                #pragma unroll
                for (int n = 0; n < 4; ++n)
                    #pragma unroll
                    for (int j = 0; j < 4; ++j) {
                        const int r = m * 16 + (l >> 4) * 4 + j;   // 0..63
                        const int c = wn * 64 + n * 16 + (l & 15);
                        sf[r * 128 + c] = acc[m][n][j];
                    }
        }
        lds_barrier();
        const int c4 = t & 31;
        const int gc = bj * 128 + c4 * 4;
        #pragma unroll
        for (int it = 0; it < 8; ++it) {
            const int r = it * 8 + (t >> 5);
            const int gr = bi * 128 + half * 64 + r;
            if (gr < NNODES && gc < NNODES) {
                f32x4 v = *(f32x4*)&sf[r * 128 + c4 * 4];
                __builtin_nontemporal_store(v, (f32x4*)&out[(size_t)gr * NN + gc]);
            }
        }
    }

    // ---- pass 2: transposed image for the mirror tile (skip on diagonal)
    if (bi != bj) {
        #pragma unroll
        for (int half = 0; half < 2; ++half) {
            lds_barrier();
            if (wn == half) {
                #pragma unroll
                for (int m = 0; m < 4; ++m)
                    #pragma unroll
                    for (int n = 0; n < 4; ++n)
                        #pragma unroll
                        for (int j = 0; j < 4; ++j) {
                            const int r = wm * 64 + m * 16 + (l >> 4) * 4 + j;
                            const int c = n * 16 + (l & 15);       // 0..63
                            sf[c * 128 + (((r >> 2) ^ (c & 7)) << 2) + (r & 3)] = acc[m][n][j];
                        }
            }
            lds_barrier();
            const int g = t & 31;
            const int gc2 = bi * 128 + g * 4;       // bi <= 77 -> in range
            #pragma unroll
            for (int it = 0; it < 8; ++it) {
                const int rt = it * 8 + (t >> 5);   // 0..63 within half
                const int gr2 = bj * 128 + half * 64 + rt;
                if (gr2 < NNODES) {
                    f32x4 v = *(f32x4*)&sf[rt * 128 + ((g ^ (rt & 7)) << 2)];
                    __builtin_nontemporal_store(v, (f32x4*)&out[(size_t)gr2 * NN + gc2]);
                }
            }
        }
    }
}

extern "C" void kernel_launch(void* const* d_in, const int* in_sizes, int n_in,
                              void* d_out, int out_size, void* d_ws, size_t ws_size,
                              hipStream_t stream) {
    const float* node = (const float*)d_in[0];
    const float* agg  = (const float*)d_in[1];
    const int*   nb   = (const int*)d_in[2];
    const float* W    = (const float*)d_in[3];
    const float* bias = (const float*)d_in[4];

    float* out_attr = (float*)d_out;
    float* out_adj  = (float*)d_out + (size_t)NNODES * DIM;

    char* ws = (char*)d_ws;
    unsigned short* aggh  = (unsigned short*)(ws);
    unsigned short* nodeh = (unsigned short*)(ws + 5120000);
    unsigned short* ctxh  = (unsigned short*)(ws + 10240000);
    unsigned short* wth   = (unsigned short*)(ws + 15360000);

    pre_kernel<<<2756, 256, 0, stream>>>(agg, node, W, aggh, nodeh, wth);

    adj_mfma_kernel<<<NTRI, 256, 0, stream>>>(aggh, out_adj);

    attn_ctx_kernel<<<NNODES, 256, 0, stream>>>(aggh, nb, ctxh);

    dim3 g2(2, NT);
    attr_mfma_kernel<<<g2, 256, 0, stream>>>(nodeh, ctxh, wth, bias, out_attr);
}